// Round 2
// baseline (334.550 us; speedup 1.0000x reference)
//
#include <hip/hip_runtime.h>
#include <hip/hip_bf16.h>

typedef __bf16 bf16_t;
typedef bf16_t bf16x8 __attribute__((ext_vector_type(8)));
typedef bf16_t bf16x4 __attribute__((ext_vector_type(4)));
typedef float  f32x4  __attribute__((ext_vector_type(4)));

#define BM 128
#define BN 128
#define BK 32

enum { EPI_NONE = 0, EPI_THRESH = 1, EPI_BIAS = 2 };

// C[M,N] = A[M,K] @ B[N,K]^T  (A,B bf16 row-major, K contiguous for both).
// 256 threads = 4 waves in 2x2; each wave owns 64x64 as 4x4 frags of
// 16x16x32 bf16 MFMA. CT = output store type (bf16 for intermediates,
// float for the final output).
template <int EPI, typename CT>
__global__ __launch_bounds__(256, 2)
void gemm_bt(const bf16_t* __restrict__ A, const bf16_t* __restrict__ B,
             CT* __restrict__ C, const float* __restrict__ bias,
             int M, int N, int K)
{
    __shared__ __align__(16) bf16_t As[BM][BK];
    __shared__ __align__(16) bf16_t Bs[BN][BK];

    const int lane = threadIdx.x & 63;
    const int wave = threadIdx.x >> 6;
    const int wm = wave >> 1;
    const int wn = wave & 1;
    const int m0 = blockIdx.y * BM;
    const int n0 = blockIdx.x * BN;

    // staging: each wave stages 2 chunks of 16 rows for A and B.
    // lane l covers row (l>>2), 16B at element col (l&3)*8; LDS dest is
    // wave-uniform base + lane*16 which equals row-major (row, col) here.
    const int ar = lane >> 2;
    const int ac = (lane & 3) * 8;

    const int fm   = lane & 15;        // m (or n) within 16x16 tile
    const int kq   = (lane >> 4) * 8;  // k offset for this quad
    const int quad = lane >> 4;

    f32x4 acc[4][4];
#pragma unroll
    for (int i = 0; i < 4; i++)
#pragma unroll
        for (int j = 0; j < 4; j++) acc[i][j] = {0.f, 0.f, 0.f, 0.f};

    for (int k0 = 0; k0 < K; k0 += BK) {
#pragma unroll
        for (int i = 0; i < 2; i++) {
            const int chunk = wave * 2 + i;  // 0..7, 16 rows each
            const bf16_t* ga = A + (size_t)(m0 + chunk * 16 + ar) * K + k0 + ac;
            __builtin_amdgcn_global_load_lds(
                (const __attribute__((address_space(1))) void*)ga,
                (__attribute__((address_space(3))) void*)&As[chunk * 16][0],
                16, 0, 0);
            const bf16_t* gb = B + (size_t)(n0 + chunk * 16 + ar) * K + k0 + ac;
            __builtin_amdgcn_global_load_lds(
                (const __attribute__((address_space(1))) void*)gb,
                (__attribute__((address_space(3))) void*)&Bs[chunk * 16][0],
                16, 0, 0);
        }
        __syncthreads();

        bf16x8 af[4], bfr[4];
#pragma unroll
        for (int i = 0; i < 4; i++)
            af[i] = *(const bf16x8*)&As[wm * 64 + i * 16 + fm][kq];
#pragma unroll
        for (int j = 0; j < 4; j++)
            bfr[j] = *(const bf16x8*)&Bs[wn * 64 + j * 16 + fm][kq];

#pragma unroll
        for (int i = 0; i < 4; i++)
#pragma unroll
            for (int j = 0; j < 4; j++)
                acc[i][j] = __builtin_amdgcn_mfma_f32_16x16x32_bf16(
                    af[i], bfr[j], acc[i][j], 0, 0, 0);

        __syncthreads();
    }

    // epilogue: C/D layout col=lane&15, row=quad*4+reg
#pragma unroll
    for (int i = 0; i < 4; i++) {
#pragma unroll
        for (int j = 0; j < 4; j++) {
            const int col = n0 + wn * 64 + j * 16 + fm;
            float bv = 0.f;
            if (EPI == EPI_BIAS) bv = bias[col];
#pragma unroll
            for (int r = 0; r < 4; r++) {
                const int row = m0 + wm * 64 + i * 16 + quad * 4 + r;
                float v = acc[i][j][r];
                if (EPI == EPI_THRESH) v = (fabsf(v) > 1e-3f) ? v : 0.f;
                if (EPI == EPI_BIAS) v += bv;
                C[(size_t)row * N + col] = (CT)v;
            }
        }
    }
}

// fp32 -> bf16 elementwise, 4 elements/thread, exact grid
__global__ void cvt_f32_bf16(const float* __restrict__ in,
                             bf16_t* __restrict__ out, int n4)
{
    const int i = blockIdx.x * blockDim.x + threadIdx.x;
    if (i < n4) {
        const f32x4 v = ((const f32x4*)in)[i];
        bf16x4 o;
        o[0] = (bf16_t)v[0]; o[1] = (bf16_t)v[1];
        o[2] = (bf16_t)v[2]; o[3] = (bf16_t)v[3];
        ((bf16x4*)out)[i] = o;
    }
}

// out[c][o] = bf16(in[o][c]), n x n, n % 32 == 0
__global__ void transpose_cvt(const float* __restrict__ in,
                              bf16_t* __restrict__ out, int n)
{
    __shared__ float t[32][33];
    const int bx = blockIdx.x * 32, by = blockIdx.y * 32;
    const int tx = threadIdx.x, ty = threadIdx.y;
#pragma unroll
    for (int i = 0; i < 32; i += 8)
        t[ty + i][tx] = in[(size_t)(by + ty + i) * n + bx + tx];
    __syncthreads();
#pragma unroll
    for (int i = 0; i < 32; i += 8)
        out[(size_t)(bx + ty + i) * n + by + tx] = (bf16_t)t[tx][ty + i];
}

extern "C" void kernel_launch(void* const* d_in, const int* in_sizes, int n_in,
                              void* d_out, int out_size, void* d_ws, size_t ws_size,
                              hipStream_t stream)
{
    const float* x    = (const float*)d_in[0];   // (8,4096,768) fp32
    const float* w    = (const float*)d_in[1];   // (768,768) fp32
    const float* bias = (const float*)d_in[2];   // (768,) fp32
    const float* U    = (const float*)d_in[3];   // (768,768) fp32
    const float* VT   = (const float*)d_in[4];   // (768,768) fp32
    float* out = (float*)d_out;                  // (8,4096,768) fp32

    const int D = 768;
    const int M = 8 * 4096;  // 32768
    const size_t MD = (size_t)M * D;             // 25,165,824
    const size_t DD = (size_t)D * D;             // 589,824

    char* ws = (char*)d_ws;
    bf16_t* xb  = (bf16_t*)ws;                                   // MD bf16
    bf16_t* h   = (bf16_t*)(ws + MD * 2);                        // MD bf16
    bf16_t* Ub  = (bf16_t*)(ws + MD * 4);                        // DD
    bf16_t* VTb = (bf16_t*)(ws + MD * 4 + DD * 2);               // DD
    bf16_t* Wt  = (bf16_t*)(ws + MD * 4 + DD * 4);               // DD: weight^T
    bf16_t* Wc  = (bf16_t*)(ws + MD * 4 + DD * 6);               // DD: VT@weight

    // 1) conversions to bf16
    cvt_f32_bf16<<<(int)(MD / 4 / 256), 256, 0, stream>>>(x, xb, (int)(MD / 4));
    cvt_f32_bf16<<<(int)(DD / 4 / 256), 256, 0, stream>>>(U, Ub, (int)(DD / 4));
    cvt_f32_bf16<<<(int)(DD / 4 / 256), 256, 0, stream>>>(VT, VTb, (int)(DD / 4));
    transpose_cvt<<<dim3(D / 32, D / 32), dim3(32, 8), 0, stream>>>(w, Wt, D);

    // 2) Wc[p][c] = sum_o VTb[p][o] * Wt[c][o] = (VT @ weight)[p][c]
    gemm_bt<EPI_NONE, bf16_t><<<dim3(D / BN, D / BM), 256, 0, stream>>>(
        VTb, Wt, Wc, nullptr, D, D, D);
    // 3) h = threshold(x @ U^T), stored bf16
    gemm_bt<EPI_THRESH, bf16_t><<<dim3(D / BN, M / BM), 256, 0, stream>>>(
        xb, Ub, h, nullptr, M, D, D);
    // 4) out = h @ Wc^T + bias  (== ((h @ W^T) @ VT^T) + bias), fp32 store
    gemm_bt<EPI_BIAS, float><<<dim3(D / BN, M / BM), 256, 0, stream>>>(
        h, Wc, out, bias, M, D, D);
}

// Round 3
// 313.047 us; speedup vs baseline: 1.0687x; 1.0687x over previous
//
#include <hip/hip_runtime.h>
#include <hip/hip_bf16.h>

typedef __bf16 bf16_t;
typedef bf16_t bf16x8 __attribute__((ext_vector_type(8)));
typedef bf16_t bf16x4 __attribute__((ext_vector_type(4)));
typedef float  f32x4  __attribute__((ext_vector_type(4)));

#define BM 128
#define BN 128
#define BK 64   // elements; a row is 8 chunks of 8 bf16 (16B each)

enum { EPI_NONE = 0, EPI_THRESH = 1, EPI_BIAS = 2 };

// LDS tile layout: 1024 16-byte units; unit(row, chunk) = row*8 + (chunk ^ (row&7)).
// The XOR swizzle is applied on the GLOBAL side of global_load_lds (lane picks
// which chunk it fetches, still within the row's 128B segment -> coalesced),
// so the hardware's lds_base + lane*16 contiguity constraint is satisfied,
// and fragment ds_read_b128s hit banks at most 2-way (free).

template <int EPI, typename CT>
__device__ __forceinline__
void gemm_tile(const bf16_t* __restrict__ A, const bf16_t* __restrict__ B,
               CT* __restrict__ C, const float* __restrict__ bias,
               int m0, int n0, int N, int K,
               bf16_t* As, bf16_t* Bs)
{
    const int lane = threadIdx.x & 63;
    const int wave = threadIdx.x >> 6;
    const int wm = wave >> 1;
    const int wn = wave & 1;

    // staging: lane covers LDS unit (wave*256 + i*64 + lane)
    const int srow = lane >> 3;                        // row offset within 8-row group
    const int scg  = (lane & 7) ^ ((lane >> 3) & 7);   // swizzled global chunk

    // fragment addressing (16x16x32)
    const int fm = lane & 15;
    const int q  = lane >> 4;
    const int fsw = fm & 7;

    f32x4 acc[4][4];
#pragma unroll
    for (int i = 0; i < 4; i++)
#pragma unroll
        for (int j = 0; j < 4; j++) acc[i][j] = {0.f, 0.f, 0.f, 0.f};

    for (int k0 = 0; k0 < K; k0 += BK) {
#pragma unroll
        for (int i = 0; i < 4; i++) {
            const int ubase = wave * 256 + i * 64;     // 16B-unit base (wave-uniform)
            const int row   = (ubase >> 3) + srow;     // wave*32 + i*8 + srow
            const bf16_t* ga = A + (size_t)(m0 + row) * K + k0 + scg * 8;
            __builtin_amdgcn_global_load_lds(
                (const __attribute__((address_space(1))) void*)ga,
                (__attribute__((address_space(3))) void*)(As + (size_t)ubase * 8),
                16, 0, 0);
            const bf16_t* gb = B + (size_t)(n0 + row) * K + k0 + scg * 8;
            __builtin_amdgcn_global_load_lds(
                (const __attribute__((address_space(1))) void*)gb,
                (__attribute__((address_space(3))) void*)(Bs + (size_t)ubase * 8),
                16, 0, 0);
        }
        __syncthreads();

#pragma unroll
        for (int h = 0; h < 2; h++) {
            bf16x8 af[4], bfr[4];
#pragma unroll
            for (int i = 0; i < 4; i++) {
                const int row = wm * 64 + i * 16 + fm;
                af[i] = *(const bf16x8*)(As + (size_t)(row * 8 + ((h * 4 + q) ^ fsw)) * 8);
            }
#pragma unroll
            for (int j = 0; j < 4; j++) {
                const int row = wn * 64 + j * 16 + fm;
                bfr[j] = *(const bf16x8*)(Bs + (size_t)(row * 8 + ((h * 4 + q) ^ fsw)) * 8);
            }
#pragma unroll
            for (int i = 0; i < 4; i++)
#pragma unroll
                for (int j = 0; j < 4; j++)
                    acc[i][j] = __builtin_amdgcn_mfma_f32_16x16x32_bf16(
                        af[i], bfr[j], acc[i][j], 0, 0, 0);
        }
        __syncthreads();
    }

    // epilogue: C/D layout col=lane&15, row=quad*4+reg
#pragma unroll
    for (int i = 0; i < 4; i++) {
#pragma unroll
        for (int j = 0; j < 4; j++) {
            const int col = n0 + wn * 64 + j * 16 + fm;
            float bv = 0.f;
            if (EPI == EPI_BIAS) bv = bias[col];
#pragma unroll
            for (int r = 0; r < 4; r++) {
                const int row = m0 + wm * 64 + i * 16 + q * 4 + r;
                float v = acc[i][j][r];
                if (EPI == EPI_THRESH) v = (fabsf(v) > 1e-3f) ? v : 0.f;
                if (EPI == EPI_BIAS) v += bv;
                C[(size_t)row * N + col] = (CT)v;
            }
        }
    }
}

// dispatch 2: h = thresh(xb @ Ub^T) [blocks 0..1535] and Wc = VTb @ Wt^T
// [blocks 1536..1571] -- independent, run concurrently in one dispatch.
__global__ __launch_bounds__(256)
void gemm_h_wc(const bf16_t* __restrict__ xb, const bf16_t* __restrict__ Ub,
               bf16_t* __restrict__ h,
               const bf16_t* __restrict__ VTb, const bf16_t* __restrict__ Wt,
               bf16_t* __restrict__ Wc)
{
    __shared__ __align__(16) bf16_t As[BM * BK];
    __shared__ __align__(16) bf16_t Bs[BN * BK];
    const int b = blockIdx.x;
    if (b < 1536) {
        gemm_tile<EPI_THRESH, bf16_t>(xb, Ub, h, nullptr,
                                      (b / 6) * BM, (b % 6) * BN, 768, 768, As, Bs);
    } else {
        const int b2 = b - 1536;
        gemm_tile<EPI_NONE, bf16_t>(VTb, Wt, Wc, nullptr,
                                    (b2 / 6) * BM, (b2 % 6) * BN, 768, 768, As, Bs);
    }
}

// dispatch 3: out = h @ Wc^T + bias (fp32 store)
__global__ __launch_bounds__(256)
void gemm_out(const bf16_t* __restrict__ h, const bf16_t* __restrict__ Wc,
              float* __restrict__ out, const float* __restrict__ bias)
{
    __shared__ __align__(16) bf16_t As[BM * BK];
    __shared__ __align__(16) bf16_t Bs[BN * BK];
    const int b = blockIdx.x;
    gemm_tile<EPI_BIAS, float>(h, Wc, out, bias,
                               (b / 6) * BM, (b % 6) * BN, 768, 768, As, Bs);
}

// dispatch 1: all fp32->bf16 conversions + weight transpose in one kernel.
// blocks [0,24576): x cvt; [24576,25152): U; [25152,25728): VT; [25728,26304): w^T
__global__ __launch_bounds__(256)
void prep(const float* __restrict__ x, const float* __restrict__ U,
          const float* __restrict__ VT, const float* __restrict__ w,
          bf16_t* __restrict__ xb, bf16_t* __restrict__ Ub,
          bf16_t* __restrict__ VTb, bf16_t* __restrict__ Wt)
{
    __shared__ float tt[32][33];
    const int b = blockIdx.x;
    if (b < 25728) {
        const float* src; bf16_t* dst; int i;
        if (b < 24576)      { src = x;  dst = xb;  i = b * 256 + threadIdx.x; }
        else if (b < 25152) { src = U;  dst = Ub;  i = (b - 24576) * 256 + threadIdx.x; }
        else                { src = VT; dst = VTb; i = (b - 25152) * 256 + threadIdx.x; }
        const f32x4 v = ((const f32x4*)src)[i];
        bf16x4 o;
        o[0] = (bf16_t)v[0]; o[1] = (bf16_t)v[1];
        o[2] = (bf16_t)v[2]; o[3] = (bf16_t)v[3];
        ((bf16x4*)dst)[i] = o;
    } else {
        const int t = b - 25728;              // 0..575
        const int bx = (t % 24) * 32, by = (t / 24) * 32;
        const int tx = threadIdx.x & 31, ty = threadIdx.x >> 5;  // 32 x 8
#pragma unroll
        for (int i = 0; i < 32; i += 8)
            tt[ty + i][tx] = w[(size_t)(by + ty + i) * 768 + bx + tx];
        __syncthreads();
#pragma unroll
        for (int i = 0; i < 32; i += 8)
            Wt[(size_t)(bx + ty + i) * 768 + by + tx] = (bf16_t)tt[tx][ty + i];
    }
}

extern "C" void kernel_launch(void* const* d_in, const int* in_sizes, int n_in,
                              void* d_out, int out_size, void* d_ws, size_t ws_size,
                              hipStream_t stream)
{
    const float* x    = (const float*)d_in[0];   // (8,4096,768) fp32
    const float* w    = (const float*)d_in[1];   // (768,768) fp32
    const float* bias = (const float*)d_in[2];   // (768,) fp32
    const float* U    = (const float*)d_in[3];   // (768,768) fp32
    const float* VT   = (const float*)d_in[4];   // (768,768) fp32
    float* out = (float*)d_out;                  // (8,4096,768) fp32

    const int D = 768;
    const int M = 8 * 4096;                      // 32768
    const size_t MD = (size_t)M * D;
    const size_t DD = (size_t)D * D;

    char* ws = (char*)d_ws;
    bf16_t* xb  = (bf16_t*)ws;                         // MD bf16
    bf16_t* h   = (bf16_t*)(ws + MD * 2);              // MD bf16
    bf16_t* Ub  = (bf16_t*)(ws + MD * 4);              // DD
    bf16_t* VTb = (bf16_t*)(ws + MD * 4 + DD * 2);     // DD
    bf16_t* Wt  = (bf16_t*)(ws + MD * 4 + DD * 4);     // DD: weight^T
    bf16_t* Wc  = (bf16_t*)(ws + MD * 4 + DD * 6);     // DD: VT@weight

    // 1) conversions + transpose fused
    prep<<<26304, 256, 0, stream>>>(x, U, VT, w, xb, Ub, VTb, Wt);
    // 2) h = thresh(xb @ Ub^T)  +  Wc = (VT @ weight) in the same dispatch
    gemm_h_wc<<<1536 + 36, 256, 0, stream>>>(xb, Ub, h, VTb, Wt, Wc);
    // 3) out = h @ Wc^T + bias  (== ((h @ W^T) @ VT^T) + bias)
    gemm_out<<<1536, 256, 0, stream>>>(h, Wc, out, bias);
}